// Round 4
// baseline (605.070 us; speedup 1.0000x reference)
//
#include <hip/hip_runtime.h>
#include <hip/hip_bf16.h>

#define HH 768
#define WW 768
#define HWSZ (HH*WW)
#define BN_EPS 1e-5f

typedef __attribute__((ext_vector_type(8))) short bf16x8;
typedef __attribute__((ext_vector_type(4))) float f32x4;

__device__ __forceinline__ float bf2f(unsigned short u) {
  union { unsigned int i; float f; } v; v.i = ((unsigned int)u) << 16; return v.f;
}
__device__ __forceinline__ unsigned short f2bf(float f) {
  union { float f; unsigned int i; } v; v.f = f;
  unsigned int x = v.i;
  return (unsigned short)((x + 0x7fffu + ((x >> 16) & 1u)) >> 16);
}
__device__ __forceinline__ float ldf(const void* p, int i, int flag) {
  return flag ? bf2f(((const unsigned short*)p)[i]) : ((const float*)p)[i];
}

// ---------------- dtype detect (bn1_v ~ U(0.5,1.5)) ----------------
__global__ void k_flag(const unsigned short* __restrict__ v1raw, int* __restrict__ flag) {
  if (threadIdx.x == 0) {
    int ok = 1;
    #pragma unroll
    for (int j = 0; j < 4; ++j) {
      unsigned short u = v1raw[2*j];
      if (u < 0x3E00u || u > 0x4040u) ok = 0;
    }
    *flag = ok;   // 1 = bf16 inputs, 0 = fp32 inputs
  }
}

// ---------------- canonicalize float tensor -> bf16 ----------------
__global__ void k_cvt(unsigned short* __restrict__ dst, const void* __restrict__ src,
                      int n, const int* __restrict__ flagp) {
  int flag = *flagp;
  for (int i = blockIdx.x * blockDim.x + threadIdx.x; i < n; i += gridDim.x * blockDim.x)
    dst[i] = flag ? ((const unsigned short*)src)[i]
                  : f2bf(((const float*)src)[i]);
}

// ---------------- prep: weight reorder + BN fold ----------------
__global__ void k_prep(const void* __restrict__ w2, const void* __restrict__ c1b,
                       const void* __restrict__ g1, const void* __restrict__ b1,
                       const void* __restrict__ m1, const void* __restrict__ v1,
                       const void* __restrict__ c2b, const void* __restrict__ g2,
                       const void* __restrict__ b2, const void* __restrict__ m2,
                       const void* __restrict__ v2, const void* __restrict__ w1,
                       const void* __restrict__ fb1, const void* __restrict__ fw2,
                       const void* __restrict__ fb2,
                       const int* __restrict__ flagp,
                       unsigned short* __restrict__ A2, float* __restrict__ cst)
{
  int flag = *flagp;
  int tid = threadIdx.x;
  float* wc1   = cst;            // 864
  float* bias1 = cst + 864;      // 32
  float* sc1   = cst + 896;      // 32
  float* sh1   = cst + 928;      // 32
  float* bias2 = cst + 960;      // 64
  float* sc2   = cst + 1024;     // 64
  float* sh2   = cst + 1088;     // 64
  float* fb1c  = cst + 1152;     // 128
  float* w2c   = cst + 1280;     // 512
  float* fb2c  = cst + 1792;     // 4
  if (tid < 32) {
    float s = ldf(g1, tid, flag) * rsqrtf(ldf(v1, tid, flag) + BN_EPS);
    sc1[tid] = s;
    sh1[tid] = ldf(b1, tid, flag) - ldf(m1, tid, flag) * s;
    bias1[tid] = ldf(c1b, tid, flag);
  }
  if (tid < 64) {
    float s = ldf(g2, tid, flag) * rsqrtf(ldf(v2, tid, flag) + BN_EPS);
    sc2[tid] = s;
    sh2[tid] = ldf(b2, tid, flag) - ldf(m2, tid, flag) * s;
    bias2[tid] = ldf(c2b, tid, flag);
  }
  if (tid < 128) fb1c[tid] = ldf(fb1, tid, flag);
  if (tid < 4)   fb2c[tid] = ldf(fb2, tid, flag);
  for (int i = tid; i < 512; i += 256) w2c[i] = ldf(fw2, i, flag);
  for (int idx = tid; idx < 27*32; idx += 256) {
    int k = idx >> 5, co = idx & 31;
    wc1[idx] = ldf(w1, co*27 + k, flag);
  }
  for (int idx = tid; idx < 80*288; idx += 256) {
    int o = idx / 288, k = idx % 288, tap = k >> 5, ci = k & 31;
    A2[idx] = (o < 64) ? f2bf(ldf(w2, (o*32 + ci)*9 + tap, flag)) : (unsigned short)0;
  }
}

// ---------------- conv1 (3->32) + relu + bn1 -> NHWC bf16; flag-aware img load ----------------
__global__ __launch_bounds__(256) void k_conv1(const void* __restrict__ img,
    const int* __restrict__ flagp, const float* __restrict__ cst,
    unsigned short* __restrict__ feat1)
{
  const float* wc1   = cst;
  const float* bias1 = cst + 864;
  const float* sc1   = cst + 896;
  const float* sh1   = cst + 928;
  int flag = *flagp;
  __shared__ float tile[3][18][18];
  int tx = threadIdx.x, ty = threadIdx.y;
  int tid = ty * 16 + tx;
  int x0 = blockIdx.x * 16, y0 = blockIdx.y * 16;
  for (int idx = tid; idx < 3*18*18; idx += 256) {
    int ci = idx / 324, rem = idx % 324, r = rem / 18, cc = rem % 18;
    int gy = y0 - 1 + r, gx = x0 - 1 + cc;
    float v = 0.f;
    if (gy >= 0 && gy < HH && gx >= 0 && gx < WW)
      v = ldf(img, ci*HWSZ + gy*WW + gx, flag);
    tile[ci][r][cc] = v;
  }
  __syncthreads();
  float acc[32];
  #pragma unroll
  for (int c = 0; c < 32; ++c) acc[c] = 0.f;
  #pragma unroll
  for (int ci = 0; ci < 3; ++ci)
    #pragma unroll
    for (int ky = 0; ky < 3; ++ky)
      #pragma unroll
      for (int kx = 0; kx < 3; ++kx) {
        float v = tile[ci][ty + ky][tx + kx];
        const float* wr = wc1 + (ci*9 + ky*3 + kx) * 32;
        #pragma unroll
        for (int c = 0; c < 32; ++c) acc[c] += v * wr[c];
      }
  int gy = y0 + ty, gx = x0 + tx;
  unsigned short* dst = feat1 + (gy*WW + gx) * 32;
  #pragma unroll
  for (int g = 0; g < 4; ++g) {
    bf16x8 pack;
    #pragma unroll
    for (int e = 0; e < 8; ++e) {
      int c = g*8 + e;
      float r = fmaxf(acc[c] + bias1[c], 0.f);
      float f = r * sc1[c] + sh1[c];
      pack[e] = (short)f2bf(f);
    }
    *(bf16x8*)(dst + g*8) = pack;
  }
}

// ---------------- LDS staging for conv2 ----------------
__device__ __forceinline__ void stage_tile(unsigned short* tile,
    const unsigned short* __restrict__ feat1, int y, int x0, int tid)
{
  for (int idx = tid; idx < 3*130*4; idx += 256) {
    int q = idx & 3, p = (idx >> 2) % 130, r = idx / 520;
    int gy = y - 1 + r, gx = x0 - 1 + p;
    uint4 val = make_uint4(0u, 0u, 0u, 0u);
    if (gy >= 0 && gy < HH && gx >= 0 && gx < WW)
      val = *(const uint4*)(feat1 + (gy*WW + gx)*32 + q*8);
    *(uint4*)(tile + (r*130 + p)*40 + q*8) = val;
  }
}

// ---------------- conv2 (32->64) implicit GEMM MFMA -> CHW fp32 ----------------
__global__ __launch_bounds__(256) void k_conv2_full(const unsigned short* __restrict__ feat1,
    const unsigned short* __restrict__ A2, const float* __restrict__ cst,
    float* __restrict__ feat2)
{
  const float* bias2 = cst + 960;
  const float* sc2   = cst + 1024;
  const float* sh2   = cst + 1088;
  __shared__ unsigned short tile[3 * 130 * 40];
  int tid = threadIdx.x;
  int y = blockIdx.y, x0 = blockIdx.x * 128;
  stage_tile(tile, feat1, y, x0, tid);
  __syncthreads();
  int w = tid >> 6, lane = tid & 63, quad = lane >> 4, l16 = lane & 15;
  int m = w * 16 + l16;
  f32x4 acc[8];
  #pragma unroll
  for (int i = 0; i < 8; ++i) acc[i] = (f32x4){0.f, 0.f, 0.f, 0.f};
  #pragma unroll
  for (int t = 0; t < 9; ++t) {
    int ky = t / 3, kx = t % 3;
    bf16x8 a = *(const bf16x8*)(A2 + m*288 + t*32 + quad*8);
    #pragma unroll
    for (int i = 0; i < 8; ++i) {
      int px = i*16 + l16 + kx;
      bf16x8 b = *(const bf16x8*)(tile + (ky*130 + px)*40 + quad*8);
      acc[i] = __builtin_amdgcn_mfma_f32_16x16x32_bf16(a, b, acc[i], 0, 0, 0);
    }
  }
  #pragma unroll
  for (int r = 0; r < 4; ++r) {
    int c = w*16 + quad*4 + r;
    float bs = bias2[c], s = sc2[c], sh = sh2[c];
    float* dst = feat2 + c*HWSZ + y*WW;
    #pragma unroll
    for (int i = 0; i < 8; ++i) {
      float v = fmaxf(acc[i][r] + bs, 0.f) * s + sh;
      dst[x0 + i*16 + l16] = v;
    }
  }
}

// ---------------- conv2 chunked fallback ----------------
__global__ __launch_bounds__(256) void k_conv2_c16(const unsigned short* __restrict__ feat1,
    const unsigned short* __restrict__ A2, const float* __restrict__ cst,
    float* __restrict__ chunk, int c0, int cnw)
{
  const float* bias2 = cst + 960;
  const float* sc2   = cst + 1024;
  const float* sh2   = cst + 1088;
  __shared__ unsigned short tile[3 * 130 * 40];
  int tid = threadIdx.x;
  int y = blockIdx.y, x0 = blockIdx.x * 128;
  stage_tile(tile, feat1, y, x0, tid);
  __syncthreads();
  int w = tid >> 6, lane = tid & 63, quad = lane >> 4, l16 = lane & 15;
  int m = c0 + l16;
  f32x4 acc[2];
  acc[0] = (f32x4){0.f,0.f,0.f,0.f};
  acc[1] = (f32x4){0.f,0.f,0.f,0.f};
  #pragma unroll
  for (int t = 0; t < 9; ++t) {
    int ky = t / 3, kx = t % 3;
    bf16x8 a = *(const bf16x8*)(A2 + m*288 + t*32 + quad*8);
    #pragma unroll
    for (int i = 0; i < 2; ++i) {
      int px = w*32 + i*16 + l16 + kx;
      bf16x8 b = *(const bf16x8*)(tile + (ky*130 + px)*40 + quad*8);
      acc[i] = __builtin_amdgcn_mfma_f32_16x16x32_bf16(a, b, acc[i], 0, 0, 0);
    }
  }
  #pragma unroll
  for (int r = 0; r < 4; ++r) {
    int cl = quad*4 + r;
    if (cl < cnw) {
      int c = c0 + cl;
      float bs = bias2[c], s = sc2[c], sh = sh2[c];
      float* dst = chunk + cl*HWSZ + y*WW;
      #pragma unroll
      for (int i = 0; i < 2; ++i) {
        float v = fmaxf(acc[i][r] + bs, 0.f) * s + sh;
        dst[x0 + w*32 + i*16 + l16] = v;
      }
    }
  }
}

// ---------------- segmented y-cumsum in-place + per-segment column totals ----------------
// grid: 64ch x 3 xblk x 12 yseg = 2304 blocks; seg = 64 rows.
__global__ __launch_bounds__(256) void k_csy_seg(float* __restrict__ feat2,
                                                 float* __restrict__ tot) {
  int bid = blockIdx.x;
  int c = bid & 63, rest = bid >> 6;
  int xb = rest % 3, ys = rest / 3;
  int x = xb * 256 + threadIdx.x;
  float* p = feat2 + c*HWSZ + (ys*64)*WW + x;
  float run = 0.f;
  for (int yb = 0; yb < 64; yb += 16) {
    float v[16];
    #pragma unroll
    for (int j = 0; j < 16; ++j) v[j] = p[(yb + j) * WW];
    #pragma unroll
    for (int j = 0; j < 16; ++j) { run += v[j]; v[j] = run; }
    #pragma unroll
    for (int j = 0; j < 16; ++j) p[(yb + j) * WW] = v[j];
  }
  tot[(c*12 + ys)*768 + x] = run;
}

// ---------------- scan segment totals -> exclusive carries (in place) ----------------
__global__ __launch_bounds__(256) void k_yscan(float* __restrict__ tot) {
  int t = blockIdx.x * 256 + threadIdx.x;   // 64*768
  int c = t / 768, x = t % 768;
  float* p = tot + c*12*768 + x;
  float run = 0.f;
  #pragma unroll
  for (int s = 0; s < 12; ++s) {
    float v = p[s*768];
    p[s*768] = run;     // exclusive prefix
    run += v;
  }
}

// ---------------- ROI pool straight from segmented y-integral ----------------
// block = one box; 16 channel-groups of 4; cell(i,j) = sum_x (Rb_i - Ra_i)
__global__ __launch_bounds__(256) void k_roi2(const float* __restrict__ Sy,
    const float* __restrict__ carry, const int* __restrict__ boxes,
    float* __restrict__ flat)
{
  __shared__ float R[40 * 256];     // 4 ch x 10 rows x 256 px
  int b = blockIdx.x, tid = threadIdx.x;
  int xmin = boxes[b*4 + 0], ymin = boxes[b*4 + 1];
  int xmax = boxes[b*4 + 2], ymax = boxes[b*4 + 3];
  int bh = ymax - ymin, bw = xmax - xmin;
  int ry[10], yx0[5], yx1[5], xx0[5], xx1[5];
  #pragma unroll
  for (int i = 0; i < 5; ++i) {
    yx0[i] = ymin + (i*bh)/5;      yx1[i] = ymin + ((i+1)*bh + 4)/5;
    xx0[i] = xmin + (i*bw)/5;      xx1[i] = xmin + ((i+1)*bw + 4)/5;
    ry[i]   = yx0[i] - 1;          // Ra rows
    ry[5+i] = yx1[i] - 1;          // Rb rows
  }
  for (int cg = 0; cg < 16; ++cg) {
    // load 4 ch x 10 rows x bw px
    for (int idx = tid; idx < 40*256; idx += 256) {
      int r = idx >> 8, x = idx & 255;
      int cl = r / 10, ri = r % 10;
      int yy = ry[ri];
      float v = 0.f;
      if (yy >= 0 && x < bw) {
        int c = cg*4 + cl;
        int gx = xmin + x;
        v = Sy[c*HWSZ + yy*WW + gx] + carry[(c*12 + (yy >> 6))*768 + gx];
      }
      R[idx] = v;
    }
    __syncthreads();
    if (tid < 100) {
      int cl = tid / 25, cell = tid % 25, i = cell / 5, j = cell % 5;
      const float* Ra = R + (cl*10 + i) * 256;
      const float* Rb = R + (cl*10 + 5 + i) * 256;
      float s = 0.f;
      int xa = xx0[j] - xmin, xbnd = xx1[j] - xmin;
      for (int x = xa; x < xbnd; ++x) s += Rb[x] - Ra[x];
      float area = (float)((yx1[i] - yx0[i]) * (xx1[j] - xx0[j]));
      flat[b*1600 + (cg*4 + cl)*25 + cell] = s / area;
    }
    __syncthreads();
  }
}

// ---------------- fallback: full-image cumsum + corner ROI ----------------
__global__ __launch_bounds__(256) void k_csy(float* __restrict__ buf) {
  int t = blockIdx.x * 256 + threadIdx.x;
  int c = t / WW, x = t % WW;
  float* p = buf + c*HWSZ + x;
  float run = 0.f;
  for (int yb = 0; yb < HH; yb += 16) {
    float v[16];
    #pragma unroll
    for (int j = 0; j < 16; ++j) v[j] = p[(yb + j) * WW];
    #pragma unroll
    for (int j = 0; j < 16; ++j) { run += v[j]; v[j] = run; }
    #pragma unroll
    for (int j = 0; j < 16; ++j) p[(yb + j) * WW] = v[j];
  }
}
__global__ __launch_bounds__(256) void k_csx(float* __restrict__ buf) {
  int row = blockIdx.x * 4 + (threadIdx.x >> 6);
  int lane = threadIdx.x & 63;
  float* p = buf + (long)row * WW;
  float carry = 0.f;
  for (int ch = 0; ch < 12; ++ch) {
    float v = p[ch*64 + lane];
    #pragma unroll
    for (int off = 1; off < 64; off <<= 1) {
      float t = __shfl_up(v, off);
      v = (lane >= off) ? v + t : v;
    }
    v += carry;
    p[ch*64 + lane] = v;
    carry = __shfl(v, 63);
  }
}
__global__ __launch_bounds__(256) void k_roi(const float* __restrict__ integ,
    const int* __restrict__ boxes, float* __restrict__ flat, int c0, int cn)
{
  int b = blockIdx.x;
  int xmin = boxes[b*4 + 0], ymin = boxes[b*4 + 1];
  int xmax = boxes[b*4 + 2], ymax = boxes[b*4 + 3];
  int bh = ymax - ymin, bw = xmax - xmin;
  for (int idx = threadIdx.x; idx < cn*25; idx += 256) {
    int cl = idx / 25, cell = idx % 25, i = cell / 5, j = cell % 5;
    int y0 = ymin + (i*bh)/5,      y1 = ymin + ((i+1)*bh + 4)/5;
    int x0 = xmin + (j*bw)/5,      x1 = xmin + ((j+1)*bw + 4)/5;
    const float* I = integ + cl*HWSZ;
    float a  = I[(y1-1)*WW + (x1-1)];
    float bl = (y0 > 0) ? I[(y0-1)*WW + (x1-1)] : 0.f;
    float cr = (x0 > 0) ? I[(y1-1)*WW + (x0-1)] : 0.f;
    float d  = (y0 > 0 && x0 > 0) ? I[(y0-1)*WW + (x0-1)] : 0.f;
    float s = a - bl - cr + d;
    float area = (float)((y1 - y0) * (x1 - x0));
    flat[b*1600 + (c0 + cl)*25 + cell] = s / area;
  }
}

// ---------------- FC1 + relu + FC2 ----------------
__global__ __launch_bounds__(128) void k_fc(const float* __restrict__ flat,
    const unsigned short* __restrict__ w1c, const float* __restrict__ cst,
    const int* __restrict__ flagp, void* __restrict__ out)
{
  const float* fb1c = cst + 1152;
  const float* w2c  = cst + 1280;
  const float* fb2c = cst + 1792;
  __shared__ float sf[1600];
  __shared__ float hbuf[128];
  int b = blockIdx.x, t = threadIdx.x;
  for (int i = t; i < 1600; i += 128) sf[i] = flat[b*1600 + i];
  __syncthreads();
  float a = fb1c[t];
  const unsigned short* wr = w1c + t * 1600;
  for (int k = 0; k < 1600; k += 8) {
    bf16x8 wv = *(const bf16x8*)(wr + k);
    #pragma unroll
    for (int e = 0; e < 8; ++e)
      a += sf[k + e] * bf2f((unsigned short)wv[e]);
  }
  hbuf[t] = fmaxf(a, 0.f);
  __syncthreads();
  if (t < 4) {
    float a2 = fb2c[t];
    for (int k = 0; k < 128; ++k) a2 += hbuf[k] * w2c[t*128 + k];
    if (*flagp) ((unsigned short*)out)[b*4 + t] = f2bf(a2);
    else        ((float*)out)[b*4 + t] = a2;
  }
}

extern "C" void kernel_launch(void* const* d_in, const int* in_sizes, int n_in,
                              void* d_out, int out_size, void* d_ws, size_t ws_size,
                              hipStream_t stream) {
  const void* img = d_in[0];
  const int* boxes = (const int*)d_in[1];
  const void* c1w = d_in[2];  const void* c1b = d_in[3];
  const void* g1  = d_in[4];  const void* b1  = d_in[5];
  const void* m1  = d_in[6];  const void* v1  = d_in[7];
  const void* c2w = d_in[8];  const void* c2b = d_in[9];
  const void* g2  = d_in[10]; const void* b2  = d_in[11];
  const void* m2  = d_in[12]; const void* v2  = d_in[13];
  const void* fw1 = d_in[14]; const void* fb1 = d_in[15];
  const void* fw2 = d_in[16]; const void* fb2 = d_in[17];

  // ws layout:
  //   A2    @0        : 46,080
  //   cst   @46080    : 7,184 -> 53,264
  //   flag  @53264    : 16    -> 53,280
  //   tot   @53280    : 64*12*768*4 = 2,359,296 -> 2,412,576 (pad -> 2,412,576)
  //   w1c   @3592224  : 409,600 -> 4,001,824
  //   flat  @4001824  : 3,276,800 -> 7,278,624
  //   feat1 @7278624  : 37,748,736 -> 45,027,360
  //   feat2 @45027360 : cn*589,824*4
  char* ws = (char*)d_ws;
  unsigned short* A2 = (unsigned short*)ws;
  float* cst = (float*)(ws + 46080);
  int* flag = (int*)(ws + 53264);
  float* tot = (float*)(ws + 53280);
  unsigned short* w1c  = (unsigned short*)(ws + 3592224);
  float* flat = (float*)(ws + 4001824);
  unsigned short* feat1 = (unsigned short*)(ws + 7278624);
  float* feat2 = (float*)(ws + 45027360);

  const size_t base = 45027360;
  int cn;
  if      (ws_size >= base + 64ull*HWSZ*4) cn = 64;
  else if (ws_size >= base + 16ull*HWSZ*4) cn = 16;
  else if (ws_size >= base +  8ull*HWSZ*4) cn = 8;
  else if (ws_size >= base +  4ull*HWSZ*4) cn = 4;
  else if (ws_size >= base +  2ull*HWSZ*4) cn = 2;
  else                                     cn = 1;

  hipLaunchKernelGGL(k_flag, dim3(1), dim3(64), 0, stream,
                     (const unsigned short*)v1, flag);
  hipLaunchKernelGGL(k_cvt, dim3(128), dim3(256), 0, stream, w1c, fw1, 128*1600, flag);
  hipLaunchKernelGGL(k_prep, dim3(1), dim3(256), 0, stream,
                     c2w, c1b, g1, b1, m1, v1, c2b, g2, b2, m2, v2, c1w,
                     fb1, fw2, fb2, flag, A2, cst);
  hipLaunchKernelGGL(k_conv1, dim3(48, 48), dim3(16, 16), 0, stream,
                     img, flag, cst, feat1);

  if (cn == 64) {
    hipLaunchKernelGGL(k_conv2_full, dim3(6, 768), dim3(256), 0, stream,
                       feat1, A2, cst, feat2);
    hipLaunchKernelGGL(k_csy_seg, dim3(2304), dim3(256), 0, stream, feat2, tot);
    hipLaunchKernelGGL(k_yscan, dim3(192), dim3(256), 0, stream, tot);
    hipLaunchKernelGGL(k_roi2, dim3(512), dim3(256), 0, stream, feat2, tot, boxes, flat);
  } else {
    for (int c0 = 0; c0 < 64; c0 += cn) {
      hipLaunchKernelGGL(k_conv2_c16, dim3(6, 768), dim3(256), 0, stream,
                         feat1, A2, cst, feat2, c0, cn);
      hipLaunchKernelGGL(k_csy, dim3(cn*3), dim3(256), 0, stream, feat2);
      hipLaunchKernelGGL(k_csx, dim3(cn*192), dim3(256), 0, stream, feat2);
      hipLaunchKernelGGL(k_roi, dim3(512), dim3(256), 0, stream, feat2, boxes, flat, c0, cn);
    }
  }
  hipLaunchKernelGGL(k_fc, dim3(512), dim3(128), 0, stream, flat, w1c, cst, flag,
                     d_out);
}

// Round 5
// 333.771 us; speedup vs baseline: 1.8128x; 1.8128x over previous
//
#include <hip/hip_runtime.h>
#include <hip/hip_bf16.h>

#define HH 768
#define WW 768
#define HWSZ (HH*WW)
#define BN_EPS 1e-5f

typedef __attribute__((ext_vector_type(8))) short bf16x8;
typedef __attribute__((ext_vector_type(4))) float f32x4;

__device__ __forceinline__ float bf2f(unsigned short u) {
  union { unsigned int i; float f; } v; v.i = ((unsigned int)u) << 16; return v.f;
}
__device__ __forceinline__ unsigned short f2bf(float f) {
  union { float f; unsigned int i; } v; v.f = f;
  unsigned int x = v.i;
  return (unsigned short)((x + 0x7fffu + ((x >> 16) & 1u)) >> 16);
}
__device__ __forceinline__ float ldf(const void* p, int i, int flag) {
  return flag ? bf2f(((const unsigned short*)p)[i]) : ((const float*)p)[i];
}

// ---------------- dtype detect (bn1_v ~ U(0.5,1.5)) ----------------
__global__ void k_flag(const unsigned short* __restrict__ v1raw, int* __restrict__ flag) {
  if (threadIdx.x == 0) {
    int ok = 1;
    #pragma unroll
    for (int j = 0; j < 4; ++j) {
      unsigned short u = v1raw[2*j];
      if (u < 0x3E00u || u > 0x4040u) ok = 0;
    }
    *flag = ok;   // 1 = bf16 inputs, 0 = fp32 inputs
  }
}

// ---------------- canonicalize float tensor -> bf16 ----------------
__global__ void k_cvt(unsigned short* __restrict__ dst, const void* __restrict__ src,
                      int n, const int* __restrict__ flagp) {
  int flag = *flagp;
  for (int i = blockIdx.x * blockDim.x + threadIdx.x; i < n; i += gridDim.x * blockDim.x)
    dst[i] = flag ? ((const unsigned short*)src)[i]
                  : f2bf(((const float*)src)[i]);
}

// ---------------- prep: weight reorder + BN fold ----------------
__global__ void k_prep(const void* __restrict__ w2, const void* __restrict__ c1b,
                       const void* __restrict__ g1, const void* __restrict__ b1,
                       const void* __restrict__ m1, const void* __restrict__ v1,
                       const void* __restrict__ c2b, const void* __restrict__ g2,
                       const void* __restrict__ b2, const void* __restrict__ m2,
                       const void* __restrict__ v2, const void* __restrict__ w1,
                       const void* __restrict__ fb1, const void* __restrict__ fw2,
                       const void* __restrict__ fb2,
                       const int* __restrict__ flagp,
                       unsigned short* __restrict__ A2, float* __restrict__ cst)
{
  int flag = *flagp;
  int tid = threadIdx.x;
  float* wc1   = cst;            // 864
  float* bias1 = cst + 864;      // 32
  float* sc1   = cst + 896;      // 32
  float* sh1   = cst + 928;      // 32
  float* bias2 = cst + 960;      // 64
  float* sc2   = cst + 1024;     // 64
  float* sh2   = cst + 1088;     // 64
  float* fb1c  = cst + 1152;     // 128
  float* w2c   = cst + 1280;     // 512
  float* fb2c  = cst + 1792;     // 4
  if (tid < 32) {
    float s = ldf(g1, tid, flag) * rsqrtf(ldf(v1, tid, flag) + BN_EPS);
    sc1[tid] = s;
    sh1[tid] = ldf(b1, tid, flag) - ldf(m1, tid, flag) * s;
    bias1[tid] = ldf(c1b, tid, flag);
  }
  if (tid < 64) {
    float s = ldf(g2, tid, flag) * rsqrtf(ldf(v2, tid, flag) + BN_EPS);
    sc2[tid] = s;
    sh2[tid] = ldf(b2, tid, flag) - ldf(m2, tid, flag) * s;
    bias2[tid] = ldf(c2b, tid, flag);
  }
  if (tid < 128) fb1c[tid] = ldf(fb1, tid, flag);
  if (tid < 4)   fb2c[tid] = ldf(fb2, tid, flag);
  for (int i = tid; i < 512; i += 256) w2c[i] = ldf(fw2, i, flag);
  for (int idx = tid; idx < 27*32; idx += 256) {
    int k = idx >> 5, co = idx & 31;
    wc1[idx] = ldf(w1, co*27 + k, flag);
  }
  for (int idx = tid; idx < 80*288; idx += 256) {
    int o = idx / 288, k = idx % 288, tap = k >> 5, ci = k & 31;
    A2[idx] = (o < 64) ? f2bf(ldf(w2, (o*32 + ci)*9 + tap, flag)) : (unsigned short)0;
  }
}

// ---------------- conv1 (3->32) + relu + bn1 -> NHWC bf16 ----------------
__global__ __launch_bounds__(256) void k_conv1(const void* __restrict__ img,
    const int* __restrict__ flagp, const float* __restrict__ cst,
    unsigned short* __restrict__ feat1)
{
  const float* wc1   = cst;
  const float* bias1 = cst + 864;
  const float* sc1   = cst + 896;
  const float* sh1   = cst + 928;
  int flag = *flagp;
  __shared__ float tile[3][18][18];
  int tx = threadIdx.x, ty = threadIdx.y;
  int tid = ty * 16 + tx;
  int x0 = blockIdx.x * 16, y0 = blockIdx.y * 16;
  for (int idx = tid; idx < 3*18*18; idx += 256) {
    int ci = idx / 324, rem = idx % 324, r = rem / 18, cc = rem % 18;
    int gy = y0 - 1 + r, gx = x0 - 1 + cc;
    float v = 0.f;
    if (gy >= 0 && gy < HH && gx >= 0 && gx < WW)
      v = ldf(img, ci*HWSZ + gy*WW + gx, flag);
    tile[ci][r][cc] = v;
  }
  __syncthreads();
  float acc[32];
  #pragma unroll
  for (int c = 0; c < 32; ++c) acc[c] = 0.f;
  #pragma unroll
  for (int ci = 0; ci < 3; ++ci)
    #pragma unroll
    for (int ky = 0; ky < 3; ++ky)
      #pragma unroll
      for (int kx = 0; kx < 3; ++kx) {
        float v = tile[ci][ty + ky][tx + kx];
        const float* wr = wc1 + (ci*9 + ky*3 + kx) * 32;
        #pragma unroll
        for (int c = 0; c < 32; ++c) acc[c] += v * wr[c];
      }
  int gy = y0 + ty, gx = x0 + tx;
  unsigned short* dst = feat1 + (gy*WW + gx) * 32;
  #pragma unroll
  for (int g = 0; g < 4; ++g) {
    bf16x8 pack;
    #pragma unroll
    for (int e = 0; e < 8; ++e) {
      int c = g*8 + e;
      float r = fmaxf(acc[c] + bias1[c], 0.f);
      float f = r * sc1[c] + sh1[c];
      pack[e] = (short)f2bf(f);
    }
    *(bf16x8*)(dst + g*8) = pack;
  }
}

// ---------------- conv2 + relu + bn2 fused with tile-local 2D integral ----------------
// grid (24,24): block = x-tile [xb*32, xb*32+32) x y-seg [yb*32, yb*32+32), all 64 ch.
// Writes T[c][y][x] = 2D integral of bn2(relu(conv2)) LOCAL to the 32x32 tile.
// 4-slot LDS row ring; stage row y+2 while computing row y (one barrier/step).
__device__ __forceinline__ void stage_row(unsigned short* tile,
    const unsigned short* __restrict__ feat1, int gy, int x0, int tid)
{
  if (tid < 136) {                       // 34 px * 4 quad-chunks
    int p = tid >> 2, q = tid & 3;
    int gx = x0 - 1 + p;
    int slot = (gy + 1) & 3;
    uint4 val = make_uint4(0u, 0u, 0u, 0u);
    if (gy >= 0 && gy < HH && gx >= 0 && gx < WW)
      val = *(const uint4*)(feat1 + (gy*WW + gx)*32 + q*8);
    *(uint4*)(tile + (slot*36 + p)*40 + q*8) = val;
  }
}

__global__ __launch_bounds__(256) void k_conv2t(const unsigned short* __restrict__ feat1,
    const unsigned short* __restrict__ A2, const float* __restrict__ cst,
    float* __restrict__ T)
{
  const float* bias2 = cst + 960;
  const float* sc2   = cst + 1024;
  const float* sh2   = cst + 1088;
  __shared__ unsigned short tile[4 * 36 * 40];   // 11.25 KB, px stride 40 shorts
  int tid = threadIdx.x;
  int xb = blockIdx.x, yb = blockIdx.y;
  int x0 = xb * 32, ybase = yb * 32;
  int w = tid >> 6, lane = tid & 63, quad = lane >> 4, l16 = lane & 15;
  int m = w * 16 + l16;

  // preload all 9 A-fragments (36 VGPRs)
  bf16x8 afrag[9];
  #pragma unroll
  for (int t = 0; t < 9; ++t)
    afrag[t] = *(const bf16x8*)(A2 + m*288 + t*32 + quad*8);

  // per-lane epilogue constants: output channel = w*16 + quad*4 + r
  float bs[4], scv[4], shv[4];
  #pragma unroll
  for (int r = 0; r < 4; ++r) {
    int c = w*16 + quad*4 + r;
    bs[r] = bias2[c]; scv[r] = sc2[c]; shv[r] = sh2[c];
  }

  f32x4 ys0 = (f32x4){0.f,0.f,0.f,0.f};
  f32x4 ys1 = (f32x4){0.f,0.f,0.f,0.f};

  stage_row(tile, feat1, ybase-1, x0, tid);
  stage_row(tile, feat1, ybase,   x0, tid);
  stage_row(tile, feat1, ybase+1, x0, tid);
  __syncthreads();

  for (int dy = 0; dy < 32; ++dy) {
    int y = ybase + dy;
    stage_row(tile, feat1, y+2, x0, tid);   // async wrt compute of row y
    f32x4 acc[2];
    acc[0] = (f32x4){0.f,0.f,0.f,0.f};
    acc[1] = (f32x4){0.f,0.f,0.f,0.f};
    #pragma unroll
    for (int t = 0; t < 9; ++t) {
      int ky = t / 3, kx = t % 3;
      int slot = (y + ky) & 3;
      #pragma unroll
      for (int i = 0; i < 2; ++i) {
        int px = i*16 + l16 + kx;
        bf16x8 b = *(const bf16x8*)(tile + (slot*36 + px)*40 + quad*8);
        acc[i] = __builtin_amdgcn_mfma_f32_16x16x32_bf16(afrag[t], b, acc[i], 0, 0, 0);
      }
    }
    // epilogue: bn(relu(conv)) -> x-prefix within 32-px tile -> y-running-sum -> store
    #pragma unroll
    for (int r = 0; r < 4; ++r) {
      float v0 = fmaxf(acc[0][r] + bs[r], 0.f) * scv[r] + shv[r];
      float v1 = fmaxf(acc[1][r] + bs[r], 0.f) * scv[r] + shv[r];
      #pragma unroll
      for (int off = 1; off < 16; off <<= 1) {
        float t0 = __shfl_up(v0, off, 16);
        float t1 = __shfl_up(v1, off, 16);
        if (l16 >= off) { v0 += t0; v1 += t1; }
      }
      v1 += __shfl(v0, 15, 16);            // carry tile0-total into tile1 prefix
      ys0[r] += v0;
      ys1[r] += v1;
      float* dst = T + (size_t)(w*16 + quad*4 + r)*HWSZ + y*WW + x0;
      dst[l16]      = ys0[r];
      dst[16 + l16] = ys1[r];
    }
    __syncthreads();   // staged row y+2 visible; slot reuse safe next iter
  }
}

// ---------------- fixup: A (x-tile carries), B (y-seg carries), C (corner carries) ----------------
// A[c][y][j] = prefix_j of T[c][y][j*32+31]          (64*768*24)
// B[c][i][x] = prefix_i of T[c][i*32+31][x]          (64*24*768)
// C[c][i][j] = 2D prefix of tile totals              (64*24*24)
__global__ __launch_bounds__(256) void k_abc(const float* __restrict__ T,
    float* __restrict__ A, float* __restrict__ B, float* __restrict__ C)
{
  int c = blockIdx.x, tid = threadIdx.x;
  const float* Tc = T + (size_t)c*HWSZ;
  for (int y = tid; y < 768; y += 256) {
    float run = 0.f;
    #pragma unroll
    for (int j = 0; j < 24; ++j) {
      run += Tc[y*WW + j*32 + 31];
      A[((size_t)c*768 + y)*24 + j] = run;
    }
  }
  for (int x = tid; x < 768; x += 256) {
    float run = 0.f;
    #pragma unroll
    for (int i = 0; i < 24; ++i) {
      run += Tc[(i*32 + 31)*WW + x];
      B[((size_t)c*24 + i)*768 + x] = run;
    }
  }
  __shared__ float ldsC[24*24];
  if (tid < 24) {
    int j = tid;
    float run = 0.f;
    #pragma unroll
    for (int i = 0; i < 24; ++i) {
      run += Tc[(i*32 + 31)*WW + j*32 + 31];
      ldsC[i*24 + j] = run;               // prefix over i
    }
  }
  __syncthreads();
  if (tid < 24) {
    int i = tid;
    float run = 0.f;
    #pragma unroll
    for (int j = 0; j < 24; ++j) {
      run += ldsC[i*24 + j];
      C[((size_t)c*24 + i)*24 + j] = run; // now 2D prefix
    }
  }
}

// ---------------- ROI pool via decomposed integral ----------------
__device__ __forceinline__ float icorner(const float* __restrict__ T,
    const float* __restrict__ A, const float* __restrict__ B,
    const float* __restrict__ C, int c, int yy, int xx)
{
  // yy, xx inclusive 0-based coords (caller guarantees >= 0)
  int i = yy >> 5, j = xx >> 5;
  float v = T[(size_t)c*HWSZ + yy*WW + xx];
  if (j > 0) v += A[((size_t)c*768 + yy)*24 + (j-1)];
  if (i > 0) v += B[((size_t)c*24 + (i-1))*768 + xx];
  if (i > 0 && j > 0) v += C[((size_t)c*24 + (i-1))*24 + (j-1)];
  return v;
}

__global__ __launch_bounds__(256) void k_roi3(const float* __restrict__ T,
    const float* __restrict__ A, const float* __restrict__ B,
    const float* __restrict__ C, const int* __restrict__ boxes,
    float* __restrict__ flat)
{
  int b = blockIdx.x;
  int xmin = boxes[b*4 + 0], ymin = boxes[b*4 + 1];
  int xmax = boxes[b*4 + 2], ymax = boxes[b*4 + 3];
  int bh = ymax - ymin, bw = xmax - xmin;
  for (int idx = threadIdx.x; idx < 1600; idx += 256) {
    int c = idx / 25, cell = idx % 25, i = cell / 5, j = cell % 5;
    int y0 = ymin + (i*bh)/5,  y1 = ymin + ((i+1)*bh + 4)/5;
    int x0 = xmin + (j*bw)/5,  x1 = xmin + ((j+1)*bw + 4)/5;
    float s = icorner(T, A, B, C, c, y1-1, x1-1);
    if (y0 > 0)           s -= icorner(T, A, B, C, c, y0-1, x1-1);
    if (x0 > 0)           s -= icorner(T, A, B, C, c, y1-1, x0-1);
    if (y0 > 0 && x0 > 0) s += icorner(T, A, B, C, c, y0-1, x0-1);
    float area = (float)((y1 - y0) * (x1 - x0));
    flat[b*1600 + idx] = s / area;
  }
}

// ---------------- fallback path kernels (chunked, proven) ----------------
__global__ __launch_bounds__(256) void k_conv2_c16(const unsigned short* __restrict__ feat1,
    const unsigned short* __restrict__ A2, const float* __restrict__ cst,
    float* __restrict__ chunk, int c0, int cnw)
{
  const float* bias2 = cst + 960;
  const float* sc2   = cst + 1024;
  const float* sh2   = cst + 1088;
  __shared__ unsigned short tile[3 * 130 * 40];
  int tid = threadIdx.x;
  int y = blockIdx.y, x0 = blockIdx.x * 128;
  for (int idx = tid; idx < 3*130*4; idx += 256) {
    int q = idx & 3, p = (idx >> 2) % 130, r = idx / 520;
    int gy = y - 1 + r, gx = x0 - 1 + p;
    uint4 val = make_uint4(0u, 0u, 0u, 0u);
    if (gy >= 0 && gy < HH && gx >= 0 && gx < WW)
      val = *(const uint4*)(feat1 + (gy*WW + gx)*32 + q*8);
    *(uint4*)(tile + (r*130 + p)*40 + q*8) = val;
  }
  __syncthreads();
  int w = tid >> 6, lane = tid & 63, quad = lane >> 4, l16 = lane & 15;
  int m = c0 + l16;
  f32x4 acc[2];
  acc[0] = (f32x4){0.f,0.f,0.f,0.f};
  acc[1] = (f32x4){0.f,0.f,0.f,0.f};
  #pragma unroll
  for (int t = 0; t < 9; ++t) {
    int ky = t / 3, kx = t % 3;
    bf16x8 a = *(const bf16x8*)(A2 + m*288 + t*32 + quad*8);
    #pragma unroll
    for (int i = 0; i < 2; ++i) {
      int px = w*32 + i*16 + l16 + kx;
      bf16x8 b = *(const bf16x8*)(tile + (ky*130 + px)*40 + quad*8);
      acc[i] = __builtin_amdgcn_mfma_f32_16x16x32_bf16(a, b, acc[i], 0, 0, 0);
    }
  }
  #pragma unroll
  for (int r = 0; r < 4; ++r) {
    int cl = quad*4 + r;
    if (cl < cnw) {
      int c = c0 + cl;
      float bsv = bias2[c], s = sc2[c], sh = sh2[c];
      float* dst = chunk + cl*HWSZ + y*WW;
      #pragma unroll
      for (int i = 0; i < 2; ++i) {
        float v = fmaxf(acc[i][r] + bsv, 0.f) * s + sh;
        dst[x0 + w*32 + i*16 + l16] = v;
      }
    }
  }
}
__global__ __launch_bounds__(256) void k_csy(float* __restrict__ buf) {
  int t = blockIdx.x * 256 + threadIdx.x;
  int c = t / WW, x = t % WW;
  float* p = buf + c*HWSZ + x;
  float run = 0.f;
  for (int yb = 0; yb < HH; yb += 16) {
    float v[16];
    #pragma unroll
    for (int j = 0; j < 16; ++j) v[j] = p[(yb + j) * WW];
    #pragma unroll
    for (int j = 0; j < 16; ++j) { run += v[j]; v[j] = run; }
    #pragma unroll
    for (int j = 0; j < 16; ++j) p[(yb + j) * WW] = v[j];
  }
}
__global__ __launch_bounds__(256) void k_csx(float* __restrict__ buf) {
  int row = blockIdx.x * 4 + (threadIdx.x >> 6);
  int lane = threadIdx.x & 63;
  float* p = buf + (long)row * WW;
  float carry = 0.f;
  for (int ch = 0; ch < 12; ++ch) {
    float v = p[ch*64 + lane];
    #pragma unroll
    for (int off = 1; off < 64; off <<= 1) {
      float t = __shfl_up(v, off);
      v = (lane >= off) ? v + t : v;
    }
    v += carry;
    p[ch*64 + lane] = v;
    carry = __shfl(v, 63);
  }
}
__global__ __launch_bounds__(256) void k_roi(const float* __restrict__ integ,
    const int* __restrict__ boxes, float* __restrict__ flat, int c0, int cn)
{
  int b = blockIdx.x;
  int xmin = boxes[b*4 + 0], ymin = boxes[b*4 + 1];
  int xmax = boxes[b*4 + 2], ymax = boxes[b*4 + 3];
  int bh = ymax - ymin, bw = xmax - xmin;
  for (int idx = threadIdx.x; idx < cn*25; idx += 256) {
    int cl = idx / 25, cell = idx % 25, i = cell / 5, j = cell % 5;
    int y0 = ymin + (i*bh)/5,      y1 = ymin + ((i+1)*bh + 4)/5;
    int x0 = xmin + (j*bw)/5,      x1 = xmin + ((j+1)*bw + 4)/5;
    const float* I = integ + cl*HWSZ;
    float a  = I[(y1-1)*WW + (x1-1)];
    float bl = (y0 > 0) ? I[(y0-1)*WW + (x1-1)] : 0.f;
    float cr = (x0 > 0) ? I[(y1-1)*WW + (x0-1)] : 0.f;
    float d  = (y0 > 0 && x0 > 0) ? I[(y0-1)*WW + (x0-1)] : 0.f;
    float s = a - bl - cr + d;
    float area = (float)((y1 - y0) * (x1 - x0));
    flat[b*1600 + (c0 + cl)*25 + cell] = s / area;
  }
}

// ---------------- FC1 + relu + FC2 ----------------
__global__ __launch_bounds__(128) void k_fc(const float* __restrict__ flat,
    const unsigned short* __restrict__ w1c, const float* __restrict__ cst,
    const int* __restrict__ flagp, void* __restrict__ out)
{
  const float* fb1c = cst + 1152;
  const float* w2c  = cst + 1280;
  const float* fb2c = cst + 1792;
  __shared__ float sf[1600];
  __shared__ float hbuf[128];
  int b = blockIdx.x, t = threadIdx.x;
  for (int i = t; i < 1600; i += 128) sf[i] = flat[b*1600 + i];
  __syncthreads();
  float a = fb1c[t];
  const unsigned short* wr = w1c + t * 1600;
  for (int k = 0; k < 1600; k += 8) {
    bf16x8 wv = *(const bf16x8*)(wr + k);
    #pragma unroll
    for (int e = 0; e < 8; ++e)
      a += sf[k + e] * bf2f((unsigned short)wv[e]);
  }
  hbuf[t] = fmaxf(a, 0.f);
  __syncthreads();
  if (t < 4) {
    float a2 = fb2c[t];
    for (int k = 0; k < 128; ++k) a2 += hbuf[k] * w2c[t*128 + k];
    if (*flagp) ((unsigned short*)out)[b*4 + t] = f2bf(a2);
    else        ((float*)out)[b*4 + t] = a2;
  }
}

extern "C" void kernel_launch(void* const* d_in, const int* in_sizes, int n_in,
                              void* d_out, int out_size, void* d_ws, size_t ws_size,
                              hipStream_t stream) {
  const void* img = d_in[0];
  const int* boxes = (const int*)d_in[1];
  const void* c1w = d_in[2];  const void* c1b = d_in[3];
  const void* g1  = d_in[4];  const void* b1  = d_in[5];
  const void* m1  = d_in[6];  const void* v1  = d_in[7];
  const void* c2w = d_in[8];  const void* c2b = d_in[9];
  const void* g2  = d_in[10]; const void* b2  = d_in[11];
  const void* m2  = d_in[12]; const void* v2  = d_in[13];
  const void* fw1 = d_in[14]; const void* fb1 = d_in[15];
  const void* fw2 = d_in[16]; const void* fb2 = d_in[17];

  // ws layout:
  //   A2    @0        : 46,080
  //   cst   @46080    : 7,184 -> 53,264
  //   flag  @53264    : 16    -> 53,280  (tot slot unused now)
  //   w1c   @3592224  : 409,600 -> 4,001,824
  //   flat  @4001824  : 3,276,800 -> 7,278,624
  //   feat1 @7278624  : 37,748,736 -> 45,027,360   (A/B/C overlaid here after conv2t)
  //   T     @45027360 : 64*HWSZ*4 = 150,994,944
  char* ws = (char*)d_ws;
  unsigned short* A2 = (unsigned short*)ws;
  float* cst = (float*)(ws + 46080);
  int* flag = (int*)(ws + 53264);
  unsigned short* w1c  = (unsigned short*)(ws + 3592224);
  float* flat = (float*)(ws + 4001824);
  unsigned short* feat1 = (unsigned short*)(ws + 7278624);
  float* T = (float*)(ws + 45027360);
  // A/B/C overlay the (dead-after-conv2t) feat1 region: 4.72+4.72+0.15 MB < 37.7 MB
  float* Aarr = (float*)(ws + 7278624);
  float* Barr = Aarr + (size_t)64*768*24;
  float* Carr = Barr + (size_t)64*24*768;

  const size_t base = 45027360;
  int cn;
  if      (ws_size >= base + 64ull*HWSZ*4) cn = 64;
  else if (ws_size >= base + 16ull*HWSZ*4) cn = 16;
  else if (ws_size >= base +  8ull*HWSZ*4) cn = 8;
  else if (ws_size >= base +  4ull*HWSZ*4) cn = 4;
  else if (ws_size >= base +  2ull*HWSZ*4) cn = 2;
  else                                     cn = 1;

  hipLaunchKernelGGL(k_flag, dim3(1), dim3(64), 0, stream,
                     (const unsigned short*)v1, flag);
  hipLaunchKernelGGL(k_cvt, dim3(128), dim3(256), 0, stream, w1c, fw1, 128*1600, flag);
  hipLaunchKernelGGL(k_prep, dim3(1), dim3(256), 0, stream,
                     c2w, c1b, g1, b1, m1, v1, c2b, g2, b2, m2, v2, c1w,
                     fb1, fw2, fb2, flag, A2, cst);
  hipLaunchKernelGGL(k_conv1, dim3(48, 48), dim3(16, 16), 0, stream,
                     img, flag, cst, feat1);

  if (cn == 64) {
    hipLaunchKernelGGL(k_conv2t, dim3(24, 24), dim3(256), 0, stream,
                       feat1, A2, cst, T);
    hipLaunchKernelGGL(k_abc, dim3(64), dim3(256), 0, stream, T, Aarr, Barr, Carr);
    hipLaunchKernelGGL(k_roi3, dim3(512), dim3(256), 0, stream,
                       T, Aarr, Barr, Carr, boxes, flat);
  } else {
    for (int c0 = 0; c0 < 64; c0 += cn) {
      hipLaunchKernelGGL(k_conv2_c16, dim3(6, 768), dim3(256), 0, stream,
                         feat1, A2, cst, T, c0, cn);
      hipLaunchKernelGGL(k_csy, dim3(cn*3), dim3(256), 0, stream, T);
      hipLaunchKernelGGL(k_csx, dim3(cn*192), dim3(256), 0, stream, T);
      hipLaunchKernelGGL(k_roi, dim3(512), dim3(256), 0, stream, T, boxes, flat, c0, cn);
    }
  }
  hipLaunchKernelGGL(k_fc, dim3(512), dim3(128), 0, stream, flat, w1c, cst, flag,
                     d_out);
}